// Round 18
// baseline (47.363 us; speedup 1.0000x reference)
//
#include <hip/hip_runtime.h>
#include <math.h>

#define K_COMP 64
#define D 32
#define ICF_COLS 528
#define NCH 33               // 32 quadratic chunks (a=0..31) + 1 linear chunk (a=32)
#define SLICES 4
#define PTSW 16              // points per wave

typedef __attribute__((ext_vector_type(8))) short v8s;
typedef __attribute__((ext_vector_type(4))) float v4f;

__device__ __forceinline__ unsigned short f2bf(float f) {
  unsigned int u = __float_as_uint(f);
  unsigned int r = (u + 0x7FFFu + ((u >> 16) & 1u)) >> 16;
  return (unsigned short)r;
}
__device__ __forceinline__ v8s pack8(unsigned a, unsigned b, unsigned c, unsigned d) {
  union { unsigned u[4]; v8s s; } u;
  u.u[0] = a; u.u[1] = b; u.u[2] = c; u.u[3] = d; return u.s;
}
__device__ __forceinline__ v8s asv8(int4 v) {
  union { int4 i; v8s s; } u; u.i = v; return u.s;
}

// ------------------- prep: one block per component k (R13, verified) -------------------
// W2 layout: frag[(s*NCH + c)*64 + g*16 + krow] = 8 bf16 coeffs for
// component k = s*16+krow, feature (a=c, b=g*8+j):  c<32 -> -0.5*(M^T M)[c][b],
// c==32 -> v[b] = (M^T M mu)[b].  Constant term goes to eSa (f32 epilogue).
__global__ __launch_bounds__(64) void gmm_prep(
    const float* __restrict__ alphas, const float* __restrict__ means,
    const float* __restrict__ icf, const float* __restrict__ wg,
    const float* __restrict__ wm,
    uint4* __restrict__ W2, float* __restrict__ eSa, float* __restrict__ wwk)
{
  int k = blockIdx.x;
  int l = threadIdx.x;
  __shared__ float M[D][D + 1];
  __shared__ float mu[D], b[D], v[D];
  __shared__ float Afl[D * D];
  __shared__ float red[64];

  const float* ick = icf + (size_t)k * ICF_COLS;

  if (l < D) {
    mu[l] = means[k * D + l];
    float q = __expf(ick[l]);
    for (int c = 0; c < D; ++c) {
      float val;
      if (c < l) { int off = c * 31 - c * (c - 1) / 2; val = ick[D + off + (l - c - 1)]; }
      else if (c == l) val = q;
      else val = 0.0f;
      M[l][c] = val;
    }
  }
  __syncthreads();
  if (l < D) {
    float acc = 0.f;
    for (int c = 0; c < D; ++c) acc = fmaf(M[l][c], mu[c], acc);
    b[l] = acc;
  }
  __syncthreads();
  if (l < D) {
    float acc = 0.f;
    for (int r = 0; r < D; ++r) acc = fmaf(M[r][l], b[r], acc);
    v[l] = acc;
  }
  for (int e = l; e < D * D; e += 64) {
    int a = e >> 5, bb = e & 31;
    float acc = 0.f;
    for (int r = 0; r < D; ++r) acc = fmaf(M[r][a], M[r][bb], acc);
    Afl[e] = -0.5f * acc;
  }
  float part = 0.f;
  for (int e = l; e < D * D; e += 64) {
    float mv = M[e / D][e % D];
    part = fmaf(mv, mv, part);
  }
  red[l] = part;
  __syncthreads();
  for (int st = 32; st > 0; st >>= 1) {
    if (l < st) red[l] += red[l + st];
    __syncthreads();
  }
  if (l == 0) {
    float msq = red[0];
    float sumq = 0.f;
    for (int i = 0; i < D; ++i) sumq += ick[i];
    float bsq = 0.f;
    for (int i = 0; i < D; ++i) bsq = fmaf(b[i], b[i], bsq);
    eSa[k] = alphas[k] + sumq - 0.5f * bsq;
    float g = wg[0], mm = wm[0];
    wwk[k] = 0.5f * g * g * msq - mm * sumq;
  }
  __syncthreads();

  int s = k >> 4, krow = k & 15;
  for (int u = l; u < NCH * 4; u += 64) {
    int c = u >> 2, g = u & 3;
    unsigned int hw[4] = {0, 0, 0, 0};
    for (int j2 = 0; j2 < 8; ++j2) {
      int bb = g * 8 + j2;
      float val = (c < D) ? Afl[c * 32 + bb] : v[bb];
      hw[j2 >> 1] |= ((unsigned int)f2bf(val)) << (16 * (j2 & 1));
    }
    W2[(s * NCH + c) * 64 + g * 16 + krow] = make_uint4(hw[0], hw[1], hw[2], hw[3]);
  }
}

// ---------- main: zero LDS, zero barriers; 1 wave = 16 points x 64 k, full unroll ----------
__global__ __launch_bounds__(256) void gmm_main(
    const float* __restrict__ x, const int4* __restrict__ W2,
    const float* __restrict__ eSa, int N, float* __restrict__ partials)
{
  int tid = threadIdx.x;
  int lane = tid & 63;
  int wv = tid >> 6;
  int w = blockIdx.x * 4 + wv;           // global wave id
  int n16 = lane & 15, g = lane >> 4;

  int pt = w * PTSW + n16;
  bool pv = pt < N;
  const float* xr = x + (size_t)(pv ? pt : (N - 1)) * D;

  // per-lane K-slice of own point's row: xb[j] = x[pt][g*8 + j]
  float xb[8];
  {
    float4 a0 = *reinterpret_cast<const float4*>(xr + g * 8);
    float4 a1 = *reinterpret_cast<const float4*>(xr + g * 8 + 4);
    xb[0] = a0.x; xb[1] = a0.y; xb[2] = a0.z; xb[3] = a0.w;
    xb[4] = a1.x; xb[5] = a1.y; xb[6] = a1.z; xb[7] = a1.w;
  }

  const int4* wp = W2 + lane;
  v4f acc[SLICES];
#pragma unroll
  for (int s = 0; s < SLICES; ++s) acc[s] = (v4f){0.f, 0.f, 0.f, 0.f};

  // fully unrolled: 33 chunks x (1 scalar xa load + 12 VALU + 4 W loads + 4 MFMA);
  // independent loads pipeline freely (no barriers, no unroll-1 serialization)
#pragma unroll
  for (int c = 0; c < NCH; ++c) {
    float xa = (c < D) ? xr[c] : 1.0f;
    unsigned d0 = (unsigned)f2bf(xa * xb[0]) | ((unsigned)f2bf(xa * xb[1]) << 16);
    unsigned d1 = (unsigned)f2bf(xa * xb[2]) | ((unsigned)f2bf(xa * xb[3]) << 16);
    unsigned d2 = (unsigned)f2bf(xa * xb[4]) | ((unsigned)f2bf(xa * xb[5]) << 16);
    unsigned d3 = (unsigned)f2bf(xa * xb[6]) | ((unsigned)f2bf(xa * xb[7]) << 16);
    v8s B = pack8(d0, d1, d2, d3);
#pragma unroll
    for (int s = 0; s < SLICES; ++s)
      acc[s] = __builtin_amdgcn_mfma_f32_16x16x32_bf16(asv8(wp[(s * NCH + c) * 64]), B, acc[s], 0, 0, 0);
  }

  // ---- epilogue: +eS, per-lane lse over 16 k, merge g-groups, per-point mask, wave sum ----
  const float4* esp = reinterpret_cast<const float4*>(eSa);
  float vals[16];
#pragma unroll
  for (int s = 0; s < SLICES; ++s) {
    float4 es = esp[s * 4 + g];
    vals[s * 4 + 0] = acc[s].x + es.x;
    vals[s * 4 + 1] = acc[s].y + es.y;
    vals[s * 4 + 2] = acc[s].z + es.z;
    vals[s * 4 + 3] = acc[s].w + es.w;
  }
  float m = vals[0];
#pragma unroll
  for (int i = 1; i < 16; ++i) m = fmaxf(m, vals[i]);
  float sv = 0.f;
#pragma unroll
  for (int i = 0; i < 16; ++i) sv += __expf(vals[i] - m);
#pragma unroll
  for (int off = 16; off <= 32; off <<= 1) {
    float mo = __shfl_xor(m, off);
    float so = __shfl_xor(sv, off);
    float mn = fmaxf(m, mo);
    sv = sv * __expf(m - mn) + so * __expf(mo - mn);
    m = mn;
  }
  float lse = pv ? (m + __logf(sv)) : 0.f;
#pragma unroll
  for (int off = 8; off > 0; off >>= 1) lse += __shfl_down(lse, off);
  if (lane == 0) partials[w] = lse;
}

// ------- final: cheap tail — 2 lgammas + log ladder, float alpha-lse, f64 sums -------
__global__ __launch_bounds__(256) void gmm_final(
    const float* __restrict__ wwk, const float* __restrict__ partials, int nparts,
    const float* __restrict__ alphas, const float* __restrict__ wg,
    const float* __restrict__ wm, int N, float* __restrict__ out)
{
  int tid = threadIdx.x;
  __shared__ double sd[256];
  __shared__ float samax;
  __shared__ double s_slse, s_sa, s_ow;

  double acc = 0.0;
  for (int i = tid; i < nparts; i += 256) acc += (double)partials[i];
  sd[tid] = acc;
  __syncthreads();
  for (int st = 128; st > 0; st >>= 1) {
    if (tid < st) sd[tid] += sd[tid + st];
    __syncthreads();
  }
  if (tid == 0) s_slse = sd[0];
  __syncthreads();

  if (tid < 64) {
    float m = alphas[tid];
#pragma unroll
    for (int off = 32; off > 0; off >>= 1) m = fmaxf(m, __shfl_xor(m, off));
    if (tid == 0) samax = m;
  }
  __syncthreads();

  sd[tid] = (tid < K_COMP) ? (double)__expf(alphas[tid] - samax) : 0.0;
  __syncthreads();
  for (int st = 128; st > 0; st >>= 1) {
    if (tid < st) sd[tid] += sd[tid + st];
    __syncthreads();
  }
  if (tid == 0) s_sa = sd[0];
  __syncthreads();

  sd[tid] = (tid < K_COMP) ? (double)wwk[tid] : 0.0;
  __syncthreads();
  for (int st = 128; st > 0; st >>= 1) {
    if (tid < st) sd[tid] += sd[tid + st];
    __syncthreads();
  }
  if (tid == 0) s_ow = sd[0];
  __syncthreads();

  // multigammaln ladder: sum_{k=0..15} lgamma(a-k) = 16*lgamma(a) - sum_{k=1..15}(16-k)*log(a-k)
  double nw = (double)D + (double)wm[0] + 1.0;
  double a  = 0.5 * nw;
  double bh = a - 0.5;
  double contrib = 0.0;
  if (tid == 0)      contrib = 16.0 * lgamma(a);
  else if (tid == 1) contrib = 16.0 * lgamma(bh);
  else if (tid >= 2 && tid < 17)  { int k = tid - 1;  contrib = -(double)(16 - k) * log(a  - (double)k); }
  else if (tid >= 17 && tid < 32) { int k = tid - 16; contrib = -(double)(16 - k) * log(bh - (double)k); }
  sd[tid] = contrib;
  __syncthreads();
  for (int st = 128; st > 0; st >>= 1) {
    if (tid < st) sd[tid] += sd[tid + st];
    __syncthreads();
  }

  if (tid == 0) {
    double mg = (D * (D - 1) / 4.0) * log(M_PI) + sd[0];
    double lse_a = (double)samax + log(s_sa);
    double g = (double)wg[0];
    double C = nw * (double)D * log(g / sqrt(2.0));
    double CONST = -(double)N * D * 0.5 * log(2.0 * M_PI);
    double prior = s_ow - (double)K_COMP * (C - mg);
    out[0] = (float)(CONST + s_slse - (double)N * lse_a + prior);
  }
}

extern "C" void kernel_launch(void* const* d_in, const int* in_sizes, int n_in,
                              void* d_out, int out_size, void* d_ws, size_t ws_size,
                              hipStream_t stream)
{
  const float* alphas = (const float*)d_in[0];
  const float* means  = (const float*)d_in[1];
  const float* icf    = (const float*)d_in[2];
  const float* x      = (const float*)d_in[3];
  const float* wg     = (const float*)d_in[4];
  const float* wm     = (const float*)d_in[5];
  float* out = (float*)d_out;

  int N = in_sizes[3] / D;
  int nwaves = (N + PTSW - 1) / PTSW;       // 3125
  int nblk   = (nwaves + 3) / 4;            // 782
  int nparts = nblk * 4;                    // 3128 (pad waves write 0)

  char* wsb = (char*)d_ws;
  const size_t W2BYTES = (size_t)SLICES * NCH * 64 * 16;  // 135168
  uint4* W2  = (uint4*)wsb;
  float* eSa = (float*)(wsb + W2BYTES);
  float* wwk = eSa + K_COMP;
  float* partials = wwk + K_COMP;

  gmm_prep<<<K_COMP, 64, 0, stream>>>(alphas, means, icf, wg, wm, W2, eSa, wwk);
  gmm_main<<<nblk, 256, 0, stream>>>(x, (const int4*)W2, eSa, N, partials);
  gmm_final<<<1, 256, 0, stream>>>(wwk, partials, nparts, alphas, wg, wm, N, out);
}